// Round 4
// baseline (1337.225 us; speedup 1.0000x reference)
//
#include <hip/hip_runtime.h>
#include <cstddef>

typedef unsigned short u16;
typedef _Float16 f16x8 __attribute__((ext_vector_type(8)));
typedef float f32x4 __attribute__((ext_vector_type(4)));

#define NB  8
#define NW  5
#define NS  5
#define NC  640
#define NHW 100
#define NQ  75
#define ND  500   // S*hw descriptors
#define NDP 512   // padded cols
#define NR  7500  // Q*hw rows
#define NRP 7552  // padded rows = 59*128
#define NRT 59

// workspace byte offsets
#define OFF_SUP   ((size_t)0)           // u16 [NB][NW][NDP][NC]  26,214,400 B
#define OFF_ABF   ((size_t)26214400)    // u16 [NB][NRP][NC]      77,332,480 B
#define OFF_QRN   ((size_t)103546880)   // f32 [NB][NRP]             241,664 B
#define OFF_PROTO ((size_t)103788544)   // f32 [NB][NW][NC]          102,400 B

__device__ __forceinline__ u16 f2h_bits(float x) {
  _Float16 h = (_Float16)x;
  return __builtin_bit_cast(u16, h);
}
__device__ __forceinline__ float h2f_bits(u16 u) {
  return (float)__builtin_bit_cast(_Float16, u);
}

__device__ __forceinline__ float block_sum(float v, float* sc, int t) {
  v += __shfl_xor(v, 32, 64);
  v += __shfl_xor(v, 16, 64);
  v += __shfl_xor(v, 8, 64);
  v += __shfl_xor(v, 4, 64);
  v += __shfl_xor(v, 2, 64);
  v += __shfl_xor(v, 1, 64);
  __syncthreads();
  if ((t & 63) == 0) sc[t >> 6] = v;
  __syncthreads();
  return sc[0] + sc[1] + sc[2] + sc[3];
}

// k1: per (b,w,32-channel group). Single coalesced global pass through an LDS
// fp16 tile; per-channel descriptor-axis norms + raw proto sums from the tile.
__global__ __launch_bounds__(256) void k1_sup(const float* __restrict__ xs,
                                              u16* __restrict__ sup2,
                                              float* __restrict__ proto_g) {
  const int cc = blockIdx.x, w = blockIdx.y, b = blockIdx.z;
  const int t = threadIdx.x;
  __shared__ u16 tile[512 * 34];   // [d][c], stride 34 (17 words, odd -> spread)
  __shared__ float rn[32];
  const size_t bw = (size_t)b * NW + w;
  const float* xbase = xs + bw * NS * NC * NHW;   // [S][C][hw]
  const int cb = cc * 32;

  for (int s = 0; s < NS; s++) {
    const float4* rb = (const float4*)(xbase + ((size_t)s * NC + cb) * NHW);
    for (int i4 = t; i4 < 800; i4 += 256) {       // fully coalesced float4
      const float4 v = rb[i4];
      const int c = i4 / 25, p4 = i4 % 25;
      const int d = s * NHW + p4 * 4;
      tile[(d    ) * 34 + c] = f2h_bits(v.x);
      tile[(d + 1) * 34 + c] = f2h_bits(v.y);
      tile[(d + 2) * 34 + c] = f2h_bits(v.z);
      tile[(d + 3) * 34 + c] = f2h_bits(v.w);
    }
  }
  if (t < 384) tile[(500 + (t >> 5)) * 34 + (t & 31)] = 0;  // zero pad d 500..511
  __syncthreads();
  {
    const int c = t >> 3, part = t & 7;   // 32 c x 8 partials, from LDS
    float ss = 0.f, sm = 0.f;
    for (int d = part; d < ND; d += 8) {
      const float x = h2f_bits(tile[d * 34 + c]);
      ss += x * x; sm += x;
    }
    ss += __shfl_xor(ss, 1, 64); ss += __shfl_xor(ss, 2, 64); ss += __shfl_xor(ss, 4, 64);
    sm += __shfl_xor(sm, 1, 64); sm += __shfl_xor(sm, 2, 64); sm += __shfl_xor(sm, 4, 64);
    if (part == 0) {
      rn[c] = 1.0f / sqrtf(ss);
      proto_g[bw * NC + cb + c] = sm;     // raw sum; mean scales cancel in cosine
    }
  }
  __syncthreads();
  u16* obase = sup2 + bw * NDP * NC + cb;
  for (int idx = t; idx < 512 * 32; idx += 256) {
    const int cl = idx & 31, d = idx >> 5;
    obase[(size_t)d * NC + cl] = f2h_bits(h2f_bits(tile[d * 34 + cl]) * rn[cl]);
  }
}

// k2: per (b,q): coalesced transpose x_query -> Abf fp16 (unnormalized),
// qm/qs via explicit LDS reductions (no atomics), cosine branch -> out.
__global__ __launch_bounds__(256) void k2_query(const float* __restrict__ xq,
                                                const float* __restrict__ proto_g,
                                                const float* __restrict__ rcosp,
                                                u16* __restrict__ Abf,
                                                float* __restrict__ qrn,
                                                float* __restrict__ out) {
  const int q = blockIdx.x, b = blockIdx.y;
  const int t = threadIdx.x;
  __shared__ u16 tile[128 * 106];   // [c_local][p], stride 106 (53 words, odd)
  __shared__ float qm[NC];
  __shared__ float qs[NHW];
  __shared__ float sc[4];
  const float* xbase = xq + ((size_t)b * NQ + q) * NC * NHW;
  u16* abase = Abf + ((size_t)b * NRP + (size_t)q * NHW) * NC;

  if (t < NHW) qs[t] = 0.f;
  __syncthreads();

  for (int cc = 0; cc < 5; cc++) {          // 128-channel chunks
    const float4* rb = (const float4*)(xbase + (size_t)cc * 128 * NHW);
    for (int i4 = t; i4 < 3200; i4 += 256) {  // coalesced float4 reads
      const float4 xv = rb[i4];
      const int e = i4 * 4;
      const int p = e % NHW, cl = e / NHW;    // 4|100: never crosses a channel
      const unsigned lo = (unsigned)f2h_bits(xv.x) | ((unsigned)f2h_bits(xv.y) << 16);
      const unsigned hi = (unsigned)f2h_bits(xv.z) | ((unsigned)f2h_bits(xv.w) << 16);
      unsigned* tw = (unsigned*)&tile[cl * 106 + p];  // 8B-aligned (212*cl + 8*p4)
      tw[0] = lo; tw[1] = hi;
    }
    __syncthreads();
    if (t < 128) {                // qm: per-channel sum over p (dword reads)
      float s = 0.f;
      const unsigned* row = (const unsigned*)&tile[t * 106];
      for (int j = 0; j < 50; j++) {
        const unsigned u = row[j];
        s += h2f_bits((u16)(u & 0xffffu)) + h2f_bits((u16)(u >> 16));
      }
      qm[cc * 128 + t] = s;
    } else if (t < 228) {         // qs: per-p sumsq over this chunk's 128 c
      const int p = t - 128;
      float s = 0.f;
      for (int c = 0; c < 128; c++) {
        const float x = h2f_bits(tile[c * 106 + p]);
        s += x * x;
      }
      qs[p] += s;
    }
    {
      const int c0 = t & 63, pr = t >> 6;
      for (int p = pr; p < NHW; p += 4) {   // coalesced 128B fp16 writes
        abase[(size_t)p * NC + cc * 128 + c0]      = tile[c0 * 106 + p];
        abase[(size_t)p * NC + cc * 128 + c0 + 64] = tile[(c0 + 64) * 106 + p];
      }
    }
    __syncthreads();
  }
  if (t < NHW) qrn[(size_t)b * NRP + q * NHW + t] = 1.0f / sqrtf(qs[t]);

  // cosine: qn.pn = (qm.proto)/(|qm||proto|)
  float part = 0.f;
  for (int c = t; c < NC; c += 256) part += qm[c] * qm[c];
  const float qq = block_sum(part, sc, t);
  const float rcos = rcosp[0];
  for (int w = 0; w < NW; w++) {
    const float* pr_ = proto_g + ((size_t)b * NW + w) * NC;
    float dp = 0.f, pp = 0.f;
    for (int c = t; c < NC; c += 256) { const float pv = pr_[c]; dp += qm[c] * pv; pp += pv * pv; }
    dp = block_sum(dp, sc, t);
    pp = block_sum(pp, sc, t);
    if (t == 0) out[((size_t)b * NQ + q) * NW + w] = rcos * dp / sqrtf(qq * pp);
  }
  if (q == 0) {   // zero A pad rows [7500,7552) for this b
    u16* pz = Abf + ((size_t)b * NRP + NR) * NC;
    for (int i = t; i < (NRP - NR) * NC; i += 256) pz[i] = 0;
  }
}

// k4: per (b,w,128-row tile). NO LDS staging: A/B fragments are loaded
// directly from global (both are stored K-contiguous in MFMA frag layout),
// with a 1-slab register lookahead (X/Y named sets). LDS only holds the
// C dump for the per-row top-5 scan. No per-slab barriers.
#define LOAD_SET(p, KO) do {                          \
    p##a0 = *(const uint4*)(aptr0 + (KO));            \
    p##a1 = *(const uint4*)(aptr1 + (KO));            \
    p##a2 = *(const uint4*)(aptr2 + (KO));            \
    p##a3 = *(const uint4*)(aptr3 + (KO));            \
    p##b0 = *(const uint4*)(bptr0 + (KO));            \
    p##b1 = *(const uint4*)(bptr1 + (KO));            \
    p##b2 = *(const uint4*)(bptr2 + (KO));            \
    p##b3 = *(const uint4*)(bptr3 + (KO));            \
  } while (0)

#define BCH(v) __builtin_bit_cast(f16x8, v)

#define MFMA_SET(p) do {                                                      \
    const f16x8 A0 = BCH(p##a0), A1 = BCH(p##a1), A2 = BCH(p##a2), A3 = BCH(p##a3); \
    const f16x8 B0 = BCH(p##b0), B1 = BCH(p##b1), B2 = BCH(p##b2), B3 = BCH(p##b3); \
    acc[0][0] = __builtin_amdgcn_mfma_f32_16x16x32_f16(A0, B0, acc[0][0], 0, 0, 0); \
    acc[0][1] = __builtin_amdgcn_mfma_f32_16x16x32_f16(A0, B1, acc[0][1], 0, 0, 0); \
    acc[0][2] = __builtin_amdgcn_mfma_f32_16x16x32_f16(A0, B2, acc[0][2], 0, 0, 0); \
    acc[0][3] = __builtin_amdgcn_mfma_f32_16x16x32_f16(A0, B3, acc[0][3], 0, 0, 0); \
    acc[1][0] = __builtin_amdgcn_mfma_f32_16x16x32_f16(A1, B0, acc[1][0], 0, 0, 0); \
    acc[1][1] = __builtin_amdgcn_mfma_f32_16x16x32_f16(A1, B1, acc[1][1], 0, 0, 0); \
    acc[1][2] = __builtin_amdgcn_mfma_f32_16x16x32_f16(A1, B2, acc[1][2], 0, 0, 0); \
    acc[1][3] = __builtin_amdgcn_mfma_f32_16x16x32_f16(A1, B3, acc[1][3], 0, 0, 0); \
    acc[2][0] = __builtin_amdgcn_mfma_f32_16x16x32_f16(A2, B0, acc[2][0], 0, 0, 0); \
    acc[2][1] = __builtin_amdgcn_mfma_f32_16x16x32_f16(A2, B1, acc[2][1], 0, 0, 0); \
    acc[2][2] = __builtin_amdgcn_mfma_f32_16x16x32_f16(A2, B2, acc[2][2], 0, 0, 0); \
    acc[2][3] = __builtin_amdgcn_mfma_f32_16x16x32_f16(A2, B3, acc[2][3], 0, 0, 0); \
    acc[3][0] = __builtin_amdgcn_mfma_f32_16x16x32_f16(A3, B0, acc[3][0], 0, 0, 0); \
    acc[3][1] = __builtin_amdgcn_mfma_f32_16x16x32_f16(A3, B1, acc[3][1], 0, 0, 0); \
    acc[3][2] = __builtin_amdgcn_mfma_f32_16x16x32_f16(A3, B2, acc[3][2], 0, 0, 0); \
    acc[3][3] = __builtin_amdgcn_mfma_f32_16x16x32_f16(A3, B3, acc[3][3], 0, 0, 0); \
  } while (0)

__global__ __launch_bounds__(256, 2) void k4_dn4(const u16* __restrict__ Abf,
                                                 const u16* __restrict__ sup2,
                                                 const float* __restrict__ qrn,
                                                 const float* __restrict__ rdn4p,
                                                 const int* __restrict__ nkp,
                                                 float* __restrict__ out) {
  const int rt = blockIdx.x, w = blockIdx.y, b = blockIdx.z;
  const int t = threadIdx.x;
  const int lane = t & 63, wid = t >> 6;
  const int m = lane & 15, quad = lane >> 4;
  const int wx = wid & 1, wy = wid >> 1;

  __shared__ __align__(16) u16 cd[128 * 132];   // [col][row-padded] 33792 B
  float* t5b = (float*)cd;                      // [128][5] merge (aliases cd)

  // Fragment base pointers: global memory IS already in MFMA frag layout.
  const u16* Ab = Abf + ((size_t)b * NRP + (size_t)rt * 128 + wy * 64 + m) * NC + quad * 8;
  const u16* aptr0 = Ab;
  const u16* aptr1 = Ab + (size_t)16 * NC;
  const u16* aptr2 = Ab + (size_t)32 * NC;
  const u16* aptr3 = Ab + (size_t)48 * NC;
  const u16* Bb = sup2 + (((size_t)b * NW + w) * NDP + wx * 64 + m) * NC + quad * 8;
  const u16* bptr0 = Bb;
  const u16* bptr1 = Bb + (size_t)16 * NC;
  const u16* bptr2 = Bb + (size_t)32 * NC;
  const u16* bptr3 = Bb + (size_t)48 * NC;

  uint4 xa0, xa1, xa2, xa3, xb0, xb1, xb2, xb3;   // named scalars: stay in VGPRs
  uint4 ya0, ya1, ya2, ya3, yb0, yb1, yb2, yb3;

  float t5[5] = {-3e38f, -3e38f, -3e38f, -3e38f, -3e38f};  // sorted ascending
  const int half = t >> 7, rown = t & 127;

  LOAD_SET(x, 0);   // prime ct=0, slab0

  for (int ct = 0; ct < 4; ct++) {
    f32x4 acc[4][4];
#pragma unroll
    for (int mt = 0; mt < 4; mt++)
#pragma unroll
      for (int nt = 0; nt < 4; nt++)
        acc[mt][nt] = (f32x4){0.f, 0.f, 0.f, 0.f};

    for (int s = 0; s < 20; s += 2) {        // 2x unrolled, X/Y rotation
      const int ko = s * 32;
      LOAD_SET(y, ko + 32);                  // slab s+1 in flight
      MFMA_SET(x);                           // compute slab s
      if (s < 18) LOAD_SET(x, ko + 64);      // slab s+2 in flight
      MFMA_SET(y);                           // compute slab s+1
    }
    if (ct < 3) {                            // prefetch next chunk's slab0
      bptr0 += (size_t)128 * NC; bptr1 += (size_t)128 * NC;
      bptr2 += (size_t)128 * NC; bptr3 += (size_t)128 * NC;
      LOAD_SET(x, 0);                        // latency hidden behind dump+scan
    }

    // dump C col-major fp16: C/D layout col=lane&15, row=quad*4+reg
#pragma unroll
    for (int mt = 0; mt < 4; mt++)
#pragma unroll
      for (int nt = 0; nt < 4; nt++) {
        const int rb_ = wy * 64 + mt * 16 + quad * 4;
        const int cl = wx * 64 + nt * 16 + m;
        const unsigned lo = (unsigned)f2h_bits(acc[mt][nt].x) | ((unsigned)f2h_bits(acc[mt][nt].y) << 16);
        const unsigned hi = (unsigned)f2h_bits(acc[mt][nt].z) | ((unsigned)f2h_bits(acc[mt][nt].w) << 16);
        unsigned* dst = (unsigned*)&cd[cl * 132 + rb_];
        dst[0] = lo; dst[1] = hi;
      }
    __syncthreads();
    // streaming top-5: 2 threads per row, 64 cols each (coalesced 2B reads)
    const int dbase = ct * 128 + half * 64;
    for (int j = 0; j < 64; j++) {
      const int d = dbase + j;
      if (d >= ND) break;   // wave-uniform (skip zero pad cols 500..511)
      const float v = h2f_bits(cd[(half * 64 + j) * 132 + rown]);
      if (v > t5[0]) {
        t5[0] = v; float tmp;
        if (t5[0] > t5[1]) { tmp = t5[0]; t5[0] = t5[1]; t5[1] = tmp; }
        if (t5[1] > t5[2]) { tmp = t5[1]; t5[1] = t5[2]; t5[2] = tmp; }
        if (t5[2] > t5[3]) { tmp = t5[2]; t5[2] = t5[3]; t5[3] = tmp; }
        if (t5[3] > t5[4]) { tmp = t5[3]; t5[3] = t5[4]; t5[4] = tmp; }
      }
    }
    __syncthreads();   // scan done before next ct's dump overwrites cd
  }

  // merge the two halves' top-5 via LDS, then reduce + write
  if (half == 1) {
#pragma unroll
    for (int i = 0; i < 5; i++) t5b[rown * 5 + i] = t5[i];
  }
  __syncthreads();
  if (half == 0) {
#pragma unroll
    for (int i = 0; i < 5; i++) {
      const float v = t5b[rown * 5 + i];
      if (v > t5[0]) {
        t5[0] = v; float tmp;
        if (t5[0] > t5[1]) { tmp = t5[0]; t5[0] = t5[1]; t5[1] = tmp; }
        if (t5[1] > t5[2]) { tmp = t5[1]; t5[1] = t5[2]; t5[2] = tmp; }
        if (t5[2] > t5[3]) { tmp = t5[2]; t5[2] = t5[3]; t5[3] = tmp; }
        if (t5[3] > t5[4]) { tmp = t5[3]; t5[3] = t5[4]; t5[4] = tmp; }
      }
    }
    const int r = rt * 128 + rown;
    if (r < NR) {
      const float s = t5[0] + t5[1] + t5[2] + t5[3] + t5[4];
      // fold per-row 1/|qd| (positive scale commutes with top-k), r_dn4, 1/k
      const float contrib = s * qrn[(size_t)b * NRP + r] * rdn4p[0] / (float)nkp[0];
      const int qi = r / NHW;
      atomicAdd(&out[((size_t)b * NQ + qi) * NW + w], contrib);
    }
  }
}

extern "C" void kernel_launch(void* const* d_in, const int* in_sizes, int n_in,
                              void* d_out, int out_size, void* d_ws, size_t ws_size,
                              hipStream_t stream) {
  (void)in_sizes; (void)n_in; (void)out_size; (void)ws_size;
  const float* xs   = (const float*)d_in[0];
  const float* xq   = (const float*)d_in[1];
  const float* rcos = (const float*)d_in[2];
  const float* rdn4 = (const float*)d_in[3];
  const int*   nk   = (const int*)d_in[4];
  float* out = (float*)d_out;
  char* ws = (char*)d_ws;
  u16*   sup2  = (u16*)(ws + OFF_SUP);
  u16*   Abf   = (u16*)(ws + OFF_ABF);
  float* qrn   = (float*)(ws + OFF_QRN);
  float* proto = (float*)(ws + OFF_PROTO);

  k1_sup <<<dim3(20, NW, NB),  dim3(256), 0, stream>>>(xs, sup2, proto);
  k2_query<<<dim3(NQ, NB),     dim3(256), 0, stream>>>(xq, proto, rcos, Abf, qrn, out);
  k4_dn4 <<<dim3(NRT, NW, NB), dim3(256), 0, stream>>>(Abf, sup2, qrn, rdn4, nk, out);
}